// Round 4
// baseline (1231.282 us; speedup 1.0000x reference)
//
#include <hip/hip_runtime.h>
#include <cstdint>
#include <cstddef>

#define WAVE 64

typedef short s16x8 __attribute__((ext_vector_type(8)));
typedef float f32x4 __attribute__((ext_vector_type(4)));

__device__ __forceinline__ unsigned short f2bf(float f) {
    unsigned int u = __float_as_uint(f);
    unsigned int r = (u + 0x7fffu + ((u >> 16) & 1u)) >> 16;
    return (unsigned short)r;
}
__device__ __forceinline__ float bf2f_lo(unsigned int v) { return __uint_as_float(v << 16); }
__device__ __forceinline__ float bf2f_hi(unsigned int v) { return __uint_as_float(v & 0xffff0000u); }

// ---------------- CSR construction ----------------

__global__ __launch_bounds__(256) void k_count(const int* __restrict__ dst, int* __restrict__ cnt,
                                               const float* __restrict__ w, float* __restrict__ deg, int E) {
    int e = blockIdx.x * 256 + threadIdx.x;
    if (e < E) {
        int d = dst[e];
        atomicAdd(&cnt[d], 1);
        if (w) atomicAdd(&deg[d], w[e]);
    }
}

__global__ __launch_bounds__(256) void k_scan1(const int* __restrict__ cnt, int* __restrict__ incl,
                                               int* __restrict__ bsums, int n) {
    __shared__ int sm[256];
    int i = blockIdx.x * 256 + threadIdx.x;
    int v = (i < n) ? cnt[i] : 0;
    sm[threadIdx.x] = v;
    __syncthreads();
    for (int off = 1; off < 256; off <<= 1) {
        int t = (threadIdx.x >= off) ? sm[threadIdx.x - off] : 0;
        __syncthreads();
        sm[threadIdx.x] += t;
        __syncthreads();
    }
    if (i < n) incl[i] = sm[threadIdx.x];
    if (threadIdx.x == 255) bsums[blockIdx.x] = sm[255];
}

__global__ __launch_bounds__(512) void k_scan2(int* __restrict__ bsums, int nb) {
    __shared__ int sm[512];
    int v = (threadIdx.x < nb) ? bsums[threadIdx.x] : 0;
    sm[threadIdx.x] = v;
    __syncthreads();
    for (int off = 1; off < 512; off <<= 1) {
        int t = (threadIdx.x >= off) ? sm[threadIdx.x - off] : 0;
        __syncthreads();
        sm[threadIdx.x] += t;
        __syncthreads();
    }
    if (threadIdx.x < nb) bsums[threadIdx.x] = sm[threadIdx.x] - v;  // exclusive
}

__global__ __launch_bounds__(256) void k_scan3(const int* __restrict__ incl, const int* __restrict__ cnt,
                                               const int* __restrict__ boff, int* __restrict__ rowp,
                                               int* __restrict__ cur, int n, int Etot) {
    int i = blockIdx.x * 256 + threadIdx.x;
    if (i < n) {
        int ex = incl[i] - cnt[i] + boff[blockIdx.x];
        rowp[i] = ex;
        cur[i] = ex;
    }
    if (i == 0) rowp[n] = Etot;
}

__global__ __launch_bounds__(256) void k_scatter(const int* __restrict__ src, const int* __restrict__ dst,
                                                 const float* __restrict__ w, int* __restrict__ cur,
                                                 int* __restrict__ csrc, float* __restrict__ cw, int E) {
    int e = blockIdx.x * 256 + threadIdx.x;
    if (e < E) {
        int d = dst[e];
        int pos = atomicAdd(&cur[d], 1);
        csrc[pos] = src[e];
        if (w) cw[pos] = w[e];
    }
}

__global__ __launch_bounds__(256) void k_dinv(const float* __restrict__ deg, float* __restrict__ dinv, int N) {
    int i = blockIdx.x * 256 + threadIdx.x;
    if (i < N) dinv[i] = rsqrtf(deg[i] + 1.0f);
}

// ---------------- conversions ----------------

__global__ __launch_bounds__(256) void k_cvt_x(const float* __restrict__ in, unsigned short* __restrict__ out,
                                               int K, int Kp, long long total) {
    long long idx = (long long)blockIdx.x * 256 + threadIdx.x;
    if (idx < total) {
        int n = (int)(idx / Kp);
        int k = (int)(idx - (long long)n * Kp);
        out[idx] = (k < K) ? f2bf(in[(long long)n * K + k]) : (unsigned short)0;
    }
}

// W fp32 [K,M] -> WT bf16 [M,Kp] (rows [0,M))
__global__ __launch_bounds__(256) void k_cvt_w(const float* __restrict__ W, unsigned short* __restrict__ WT,
                                               int K, int M, int Kp) {
    int idx = blockIdx.x * 256 + threadIdx.x;
    if (idx < M * Kp) {
        int m = idx / Kp;
        int k = idx - m * Kp;
        WT[idx] = (k < K) ? f2bf(W[(long long)k * M + m]) : (unsigned short)0;
    }
}

// va rows: WT[M + t*H + h][k] = sum_c W[k][h*C+c] * a_t[h][c]   (t: 0=src, 1=dst)
__global__ __launch_bounds__(64) void k_prep_va(const float* __restrict__ W,
                                                const float* __restrict__ a_src, const float* __restrict__ a_dst,
                                                unsigned short* __restrict__ WT,
                                                int K, int M, int C, int Kp, int H) {
    int b = blockIdx.x;
    int t = b / H;
    int h = b - t * H;
    const float* a = t ? a_dst : a_src;
    int hoff = h * C;
    size_t row = (size_t)(M + t * H + h) * Kp;
    for (int k = threadIdx.x; k < Kp; k += 64) {
        float acc = 0.f;
        if (k < K) {
            for (int c = 0; c < C; c++) acc += W[(size_t)k * M + hoff + c] * a[hoff + c];
        }
        WT[row + k] = f2bf(acc);
    }
}

// ---------------- bf16 MFMA GEMM + alpha epilogue ----------------
// Cbf[N,Mp] = A[N,Kp] * BT[.,Kp]^T ; cols [0,M) -> bf16 Cbf; cols [M,M+2H) -> fp32 asb/adb

#define TBM 128
#define TBN 128
#define TBK 32
#define LDK 40

__global__ __launch_bounds__(256) void k_mfma_gemm(const unsigned short* __restrict__ A,
                                                   const unsigned short* __restrict__ BT,
                                                   unsigned short* __restrict__ Cbf,
                                                   float* __restrict__ asb, float* __restrict__ adb,
                                                   int N, int Kp, int M, int Mext, int Mp, int H) {
    __shared__ __align__(16) unsigned short As[TBM * LDK];
    __shared__ __align__(16) unsigned short Bs[TBN * LDK];
    int tid = threadIdx.x;
    int wave = tid >> 6;
    int lane = tid & 63;
    int rowBase = blockIdx.y * TBM;
    int colBase = blockIdx.x * TBN;
    int wm = (wave & 1) * 64;
    int wn = (wave >> 1) * 64;
    int l15 = lane & 15;
    int quad = lane >> 4;

    f32x4 acc[4][4];
    f32x4 z4 = {0.f, 0.f, 0.f, 0.f};
#pragma unroll
    for (int i = 0; i < 4; i++)
#pragma unroll
        for (int j = 0; j < 4; j++) acc[i][j] = z4;

    int srow = tid >> 2;
    int skg = tid & 3;
    const uint4 zero16 = {0u, 0u, 0u, 0u};

    for (int k0 = 0; k0 < Kp; k0 += TBK) {
#pragma unroll
        for (int half = 0; half < 2; half++) {
            int row = srow + half * 64;
            int gk = k0 + skg * 8;
            bool kok = (gk < Kp);
            {
                int gr = rowBase + row;
                uint4 v = zero16;
                if (kok && gr < N) v = *(const uint4*)(A + (size_t)gr * Kp + gk);
                *(uint4*)(As + row * LDK + skg * 8) = v;
            }
            {
                int gc = colBase + row;
                uint4 v = zero16;
                if (kok && gc < Mext) v = *(const uint4*)(BT + (size_t)gc * Kp + gk);
                *(uint4*)(Bs + row * LDK + skg * 8) = v;
            }
        }
        __syncthreads();

        s16x8 af[4], bfr[4];
#pragma unroll
        for (int mt = 0; mt < 4; mt++)
            af[mt] = *(const s16x8*)(As + (wm + mt * 16 + l15) * LDK + quad * 8);
#pragma unroll
        for (int nt = 0; nt < 4; nt++)
            bfr[nt] = *(const s16x8*)(Bs + (wn + nt * 16 + l15) * LDK + quad * 8);
#pragma unroll
        for (int mt = 0; mt < 4; mt++)
#pragma unroll
            for (int nt = 0; nt < 4; nt++)
                acc[mt][nt] = __builtin_amdgcn_mfma_f32_16x16x32_bf16(af[mt], bfr[nt], acc[mt][nt], 0, 0, 0);
        __syncthreads();
    }

#pragma unroll
    for (int mt = 0; mt < 4; mt++) {
#pragma unroll
        for (int r = 0; r < 4; r++) {
            int row = rowBase + wm + mt * 16 + quad * 4 + r;
            if (row < N) {
#pragma unroll
                for (int nt = 0; nt < 4; nt++) {
                    int col = colBase + wn + nt * 16 + l15;
                    float v = acc[mt][nt][r];
                    if (col < M) {
                        Cbf[(size_t)row * Mp + col] = f2bf(v);
                    } else if (asb != nullptr && col < M + 2 * H) {
                        int t = col - M;
                        if (t < H) asb[(size_t)row * H + t] = v;
                        else adb[(size_t)row * H + (t - H)] = v;
                    }
                }
            }
        }
    }
}

// ---------------- GAT aggregation: wave-parallel edge weights + shfl-broadcast gathers ----------------

__device__ __forceinline__ float lrelu02(float e) { return (e > 0.f) ? e : 0.2f * e; }

template <int CPT2, int H>
__global__ __launch_bounds__(64) void k_gat_agg(const unsigned short* __restrict__ hfeat,
                                                const float* __restrict__ as_, const float* __restrict__ ad_,
                                                const int* __restrict__ rowp, const int* __restrict__ cidx,
                                                const float* __restrict__ bias,
                                                float* __restrict__ out_f,            // final fp32 (or null)
                                                unsigned short* __restrict__ out_bf,  // next-layer bf16 (or null)
                                                int C, int ldh, int ldo, int relu) {
    int n = blockIdx.x;
    int lane = threadIdx.x;
    int HC = H * C;
    int beg = rowp[n], end = rowp[n + 1];

    int c2i[CPT2];
    bool act[CPT2];
    int hd[CPT2];
#pragma unroll
    for (int k = 0; k < CPT2; k++) {
        int c2 = 2 * (lane + k * WAVE);
        c2i[k] = c2;
        act[k] = (c2 < HC);
        hd[k] = act[k] ? (c2 / C) : 0;  // C even -> pair same head
    }

    float adn[H], msub[H], wsum[H];
#pragma unroll
    for (int h = 0; h < H; h++) {
        adn[h] = ad_[(size_t)n * H + h];
        msub[h] = lrelu02(as_[(size_t)n * H + h] + adn[h]);  // shift by self logit
        wsum[h] = 0.f;                                       // per-lane partial edge-weight sum
    }

    float accx[CPT2], accy[CPT2];
#pragma unroll
    for (int k = 0; k < CPT2; k++) {
        if (act[k]) {
            unsigned int v = *(const unsigned int*)(hfeat + (size_t)n * ldh + c2i[k]);
            accx[k] = bf2f_lo(v);  // self-loop contribution, w = exp(0) = 1
            accy[k] = bf2f_hi(v);
        } else {
            accx[k] = 0.f;
            accy[k] = 0.f;
        }
    }

    for (int base = beg; base < end; base += WAVE) {
        int cnt = end - base;
        if (cnt > WAVE) cnt = WAVE;
        // lane-parallel: edge index + weight for this chunk
        int s_l = 0;
        float w_l[H];
#pragma unroll
        for (int h = 0; h < H; h++) w_l[h] = 0.f;
        if (lane < cnt) {
            s_l = cidx[base + lane];
#pragma unroll
            for (int h = 0; h < H; h++) {
                w_l[h] = __expf(lrelu02(as_[(size_t)s_l * H + h] + adn[h]) - msub[h]);
                wsum[h] += w_l[h];
            }
        }
        // serial over chunk: broadcast s,w; gather features
        for (int j = 0; j < cnt; j++) {
            int s = __shfl(s_l, j);
            float w[H];
#pragma unroll
            for (int h = 0; h < H; h++) w[h] = __shfl(w_l[h], j);
            const unsigned short* hp = hfeat + (size_t)s * ldh;
#pragma unroll
            for (int k = 0; k < CPT2; k++) {
                if (act[k]) {
                    unsigned int v = *(const unsigned int*)(hp + c2i[k]);
                    accx[k] += w[hd[k]] * bf2f_lo(v);
                    accy[k] += w[hd[k]] * bf2f_hi(v);
                }
            }
        }
    }

    // reduce edge-weight sums across lanes (all lanes end with same value)
    float rs[H];
#pragma unroll
    for (int h = 0; h < H; h++) {
        float t = wsum[h];
        for (int off = 32; off > 0; off >>= 1) t += __shfl_xor(t, off);
        rs[h] = 1.f / (1.f + t + 1e-16f);  // +1 = self term
    }

#pragma unroll
    for (int k = 0; k < CPT2; k++) {
        int c2 = c2i[k];
        if (act[k]) {
            float o0 = accx[k] * rs[hd[k]] + bias[c2];
            float o1 = accy[k] * rs[hd[k]] + bias[c2 + 1];
            if (relu) { o0 = fmaxf(o0, 0.f); o1 = fmaxf(o1, 0.f); }
            if (out_bf) {
                unsigned int pk = (unsigned int)f2bf(o0) | ((unsigned int)f2bf(o1) << 16);
                *(unsigned int*)(out_bf + (size_t)n * ldo + c2) = pk;
            } else {
                *(float2*)(out_f + (size_t)n * HC + c2) = make_float2(o0, o1);
            }
        } else if (out_bf && c2 < ldo) {
            *(unsigned int*)(out_bf + (size_t)n * ldo + c2) = 0u;
        }
    }
}

// ---------------- GCN aggregation (bf16 in/out, pair loads) ----------------

__global__ __launch_bounds__(64) void k_gcn_agg(const unsigned short* __restrict__ hfeat, int ldh,
                                                const float* __restrict__ dinv,
                                                const int* __restrict__ rowp, const int* __restrict__ cidx,
                                                const float* __restrict__ cw, const float* __restrict__ bias,
                                                unsigned short* __restrict__ out_bf, int C, int ldo) {
    int n = blockIdx.x;
    int lane = threadIdx.x;
    float di = dinv[n];
    int beg = rowp[n], end = rowp[n + 1];
    int c2 = 2 * lane;
    bool actl = (c2 < C);  // pair (c2, c2+1); c2+1 may be pad (zero or ignored)

    float accx = 0.f, accy = 0.f;
    if (actl) {
        unsigned int v = *(const unsigned int*)(hfeat + (size_t)n * ldh + c2);
        accx = di * di * bf2f_lo(v);
        accy = di * di * bf2f_hi(v);
    }

    for (int base = beg; base < end; base += WAVE) {
        int cnt = end - base;
        if (cnt > WAVE) cnt = WAVE;
        int s_l = 0;
        float nm_l = 0.f;
        if (lane < cnt) {
            s_l = cidx[base + lane];
            nm_l = dinv[s_l] * cw[base + lane] * di;
        }
        for (int j = 0; j < cnt; j++) {
            int s = __shfl(s_l, j);
            float nm = __shfl(nm_l, j);
            if (actl) {
                unsigned int v = *(const unsigned int*)(hfeat + (size_t)s * ldh + c2);
                accx += nm * bf2f_lo(v);
                accy += nm * bf2f_hi(v);
            }
        }
    }

    if (c2 < ldo) {
        float o0 = 0.f, o1 = 0.f;
        if (c2 < C) o0 = fmaxf(accx + bias[c2], 0.f);
        if (c2 + 1 < C) o1 = fmaxf(accy + bias[c2 + 1], 0.f);
        unsigned int pk = (unsigned int)f2bf(o0) | ((unsigned int)f2bf(o1) << 16);
        *(unsigned int*)(out_bf + (size_t)n * ldo + c2) = pk;
    }
}

// ---------------- launch ----------------

extern "C" void kernel_launch(void* const* d_in, const int* in_sizes, int n_in,
                              void* d_out, int out_size, void* d_ws, size_t ws_size,
                              hipStream_t stream) {
    const int N_MOL = in_sizes[0] / 78;
    const int E_MOL = in_sizes[1] / 2;
    const int N_PRO = in_sizes[2] / 33;
    const int E_PRO = in_sizes[3] / 2;

    const float* mol_x = (const float*)d_in[0];
    const int* mol_ei = (const int*)d_in[1];
    const float* pro_x = (const float*)d_in[2];
    const int* pro_ei = (const int*)d_in[3];
    const float* pro_ew = (const float*)d_in[4];
    const float *W1 = (const float*)d_in[5], *as1 = (const float*)d_in[6], *ad1 = (const float*)d_in[7],
                *b1 = (const float*)d_in[8];
    const float *W2 = (const float*)d_in[9], *as2 = (const float*)d_in[10], *ad2 = (const float*)d_in[11],
                *b2 = (const float*)d_in[12];
    const float *W3 = (const float*)d_in[13], *as3 = (const float*)d_in[14], *ad3 = (const float*)d_in[15],
                *b3 = (const float*)d_in[16];
    const float *Wp1 = (const float*)d_in[17], *bp1 = (const float*)d_in[18];
    const float *Wp2 = (const float*)d_in[19], *aps2 = (const float*)d_in[20], *apd2 = (const float*)d_in[21],
                *bp2 = (const float*)d_in[22];
    const float *Wp3 = (const float*)d_in[23], *aps3 = (const float*)d_in[24], *apd3 = (const float*)d_in[25],
                *bp3 = (const float*)d_in[26];

    float* out_mol = (float*)d_out;
    float* out_pro = (float*)d_out + (size_t)N_MOL * 312;

    char* p = (char*)d_ws;
    auto alloc = [&](size_t bytes) -> void* {
        void* r = (void*)p;
        p += (bytes + 255) & ~(size_t)255;
        return r;
    };
    int* mol_rowp = (int*)alloc((size_t)(N_MOL + 1) * 4);
    int* mol_cur  = (int*)alloc((size_t)N_MOL * 4);
    int* mol_cnt  = (int*)alloc((size_t)N_MOL * 4);
    int* mol_csrc = (int*)alloc((size_t)E_MOL * 4);
    int* pro_rowp = (int*)alloc((size_t)(N_PRO + 1) * 4);
    int* pro_cur  = (int*)alloc((size_t)N_PRO * 4);
    int* pro_cnt  = (int*)alloc((size_t)N_PRO * 4);
    int* pro_csrc = (int*)alloc((size_t)E_PRO * 4);
    float* pro_csrw = (float*)alloc((size_t)E_PRO * 4);
    float* deg  = (float*)alloc((size_t)N_PRO * 4);
    float* dinv = (float*)alloc((size_t)N_PRO * 4);
    int* incl  = (int*)alloc((size_t)N_PRO * 4);
    int* bsums = (int*)alloc(512 * 4);
    float* asb = (float*)alloc((size_t)N_PRO * 2 * 4);
    float* adb = (float*)alloc((size_t)N_PRO * 2 * 4);
    unsigned short* hb = (unsigned short*)alloc((size_t)N_MOL * 320 * 2);  // GEMM out bf16
    unsigned short* xb = (unsigned short*)alloc((size_t)N_MOL * 320 * 2);  // activations bf16
    unsigned short* wt1 = (unsigned short*)alloc((size_t)160 * 80 * 2);    // 156 + 4 alpha rows
    unsigned short* wt2 = (unsigned short*)alloc((size_t)320 * 160 * 2);   // 312 + 4
    unsigned short* wt3 = (unsigned short*)alloc((size_t)320 * 320 * 2);   // 312 + 2
    unsigned short* wtp1 = (unsigned short*)alloc((size_t)40 * 40 * 2);
    unsigned short* wtp2 = (unsigned short*)alloc((size_t)136 * 40 * 2);   // 132 + 4
    unsigned short* wtp3 = (unsigned short*)alloc((size_t)136 * 136 * 2);  // 132 + 2
    (void)ws_size;

    const int* mol_src = mol_ei;
    const int* mol_dst = mol_ei + E_MOL;
    const int* pro_src = pro_ei;
    const int* pro_dst = pro_ei + E_PRO;

    // ---- build CSR (by dst) ----
    hipMemsetAsync(mol_cnt, 0, (size_t)N_MOL * 4, stream);
    hipMemsetAsync(pro_cnt, 0, (size_t)N_PRO * 4, stream);
    hipMemsetAsync(deg, 0, (size_t)N_PRO * 4, stream);

    k_count<<<(E_MOL + 255) / 256, 256, 0, stream>>>(mol_dst, mol_cnt, nullptr, nullptr, E_MOL);
    k_count<<<(E_PRO + 255) / 256, 256, 0, stream>>>(pro_dst, pro_cnt, pro_ew, deg, E_PRO);

    int nbM = (N_MOL + 255) / 256;
    k_scan1<<<nbM, 256, 0, stream>>>(mol_cnt, incl, bsums, N_MOL);
    k_scan2<<<1, 512, 0, stream>>>(bsums, nbM);
    k_scan3<<<nbM, 256, 0, stream>>>(incl, mol_cnt, bsums, mol_rowp, mol_cur, N_MOL, E_MOL);
    k_scatter<<<(E_MOL + 255) / 256, 256, 0, stream>>>(mol_src, mol_dst, nullptr, mol_cur, mol_csrc, nullptr, E_MOL);

    int nbP = (N_PRO + 255) / 256;
    k_scan1<<<nbP, 256, 0, stream>>>(pro_cnt, incl, bsums, N_PRO);
    k_scan2<<<1, 512, 0, stream>>>(bsums, nbP);
    k_scan3<<<nbP, 256, 0, stream>>>(incl, pro_cnt, bsums, pro_rowp, pro_cur, N_PRO, E_PRO);
    k_scatter<<<(E_PRO + 255) / 256, 256, 0, stream>>>(pro_src, pro_dst, pro_ew, pro_cur, pro_csrc, pro_csrw, E_PRO);

    k_dinv<<<(N_PRO + 255) / 256, 256, 0, stream>>>(deg, dinv, N_PRO);

    // ---- weight converts + fused alpha-vector rows ----
    auto cvtw = [&](const float* W, unsigned short* WT, int K, int M, int Kp) {
        k_cvt_w<<<(M * Kp + 255) / 256, 256, 0, stream>>>(W, WT, K, M, Kp);
    };
    cvtw(W1, wt1, 78, 156, 80);
    cvtw(W2, wt2, 156, 312, 160);
    cvtw(W3, wt3, 312, 312, 320);
    cvtw(Wp1, wtp1, 33, 33, 40);
    cvtw(Wp2, wtp2, 33, 132, 40);
    cvtw(Wp3, wtp3, 132, 132, 136);
    k_prep_va<<<4, 64, 0, stream>>>(W1, as1, ad1, wt1, 78, 156, 78, 80, 2);
    k_prep_va<<<4, 64, 0, stream>>>(W2, as2, ad2, wt2, 156, 312, 156, 160, 2);
    k_prep_va<<<2, 64, 0, stream>>>(W3, as3, ad3, wt3, 312, 312, 312, 320, 1);
    k_prep_va<<<4, 64, 0, stream>>>(Wp2, aps2, apd2, wtp2, 33, 132, 66, 40, 2);
    k_prep_va<<<2, 64, 0, stream>>>(Wp3, aps3, apd3, wtp3, 132, 132, 132, 136, 1);

    auto gemm = [&](const unsigned short* A, const unsigned short* BT, unsigned short* C,
                    float* as_o, float* ad_o, int N, int Kp, int M, int Mp, int H) {
        int Mext = (as_o != nullptr) ? (M + 2 * H) : M;
        dim3 grid((Mext + TBN - 1) / TBN, (N + TBM - 1) / TBM);
        k_mfma_gemm<<<grid, 256, 0, stream>>>(A, BT, C, as_o, ad_o, N, Kp, M, Mext, Mp, H);
    };

    // ---- mol branch ----
    {
        long long tot = (long long)N_MOL * 80;
        k_cvt_x<<<(int)((tot + 255) / 256), 256, 0, stream>>>(mol_x, xb, 78, 80, tot);
    }
    // conv1: GAT 78 -> 78, H=2 (HC=156), relu
    gemm(xb, wt1, hb, asb, adb, N_MOL, 80, 156, 160, 2);
    k_gat_agg<2, 2><<<N_MOL, 64, 0, stream>>>(hb, asb, adb, mol_rowp, mol_csrc, b1, nullptr, xb, 78, 160, 160, 1);
    // conv2: GAT 156 -> 156, H=2 (HC=312), relu
    gemm(xb, wt2, hb, asb, adb, N_MOL, 160, 312, 320, 2);
    k_gat_agg<3, 2><<<N_MOL, 64, 0, stream>>>(hb, asb, adb, mol_rowp, mol_csrc, b2, nullptr, xb, 156, 320, 320, 1);
    // conv3: GAT 312 -> 312, H=1, no relu -> fp32 out
    gemm(xb, wt3, hb, asb, adb, N_MOL, 320, 312, 320, 1);
    k_gat_agg<3, 1><<<N_MOL, 64, 0, stream>>>(hb, asb, adb, mol_rowp, mol_csrc, b3, out_mol, nullptr, 312, 320, 0, 0);

    // ---- pro branch ----
    {
        long long tot = (long long)N_PRO * 40;
        k_cvt_x<<<(int)((tot + 255) / 256), 256, 0, stream>>>(pro_x, xb, 33, 40, tot);
    }
    // gcn: 33 -> 33, relu
    gemm(xb, wtp1, hb, nullptr, nullptr, N_PRO, 40, 33, 40, 0);
    k_gcn_agg<<<N_PRO, 64, 0, stream>>>(hb, 40, dinv, pro_rowp, pro_csrc, pro_csrw, bp1, xb, 33, 40);
    // conv2: GAT 33 -> 66, H=2 (HC=132), relu
    gemm(xb, wtp2, hb, asb, adb, N_PRO, 40, 132, 136, 2);
    k_gat_agg<2, 2><<<N_PRO, 64, 0, stream>>>(hb, asb, adb, pro_rowp, pro_csrc, bp2, nullptr, xb, 66, 136, 136, 1);
    // conv3: GAT 132 -> 132, H=1, relu -> fp32 out
    gemm(xb, wtp3, hb, asb, adb, N_PRO, 136, 132, 136, 1);
    k_gat_agg<2, 1><<<N_PRO, 64, 0, stream>>>(hb, asb, adb, pro_rowp, pro_csrc, bp3, out_pro, nullptr, 132, 136, 0, 1);
}

// Round 5
// 1002.238 us; speedup vs baseline: 1.2285x; 1.2285x over previous
//
#include <hip/hip_runtime.h>
#include <cstdint>
#include <cstddef>

#define WAVE 64

typedef short s16x8 __attribute__((ext_vector_type(8)));
typedef float f32x4 __attribute__((ext_vector_type(4)));

__device__ __forceinline__ unsigned short f2bf(float f) {
    unsigned int u = __float_as_uint(f);
    unsigned int r = (u + 0x7fffu + ((u >> 16) & 1u)) >> 16;
    return (unsigned short)r;
}
__device__ __forceinline__ float bf2f_lo(unsigned int v) { return __uint_as_float(v << 16); }
__device__ __forceinline__ float bf2f_hi(unsigned int v) { return __uint_as_float(v & 0xffff0000u); }

// ---------------- CSR construction ----------------

__global__ __launch_bounds__(256) void k_count(const int* __restrict__ dst, int* __restrict__ cnt,
                                               const float* __restrict__ w, float* __restrict__ deg, int E) {
    int e = blockIdx.x * 256 + threadIdx.x;
    if (e < E) {
        int d = dst[e];
        atomicAdd(&cnt[d], 1);
        if (w) atomicAdd(&deg[d], w[e]);
    }
}

__global__ __launch_bounds__(256) void k_scan1(const int* __restrict__ cnt, int* __restrict__ incl,
                                               int* __restrict__ bsums, int n) {
    __shared__ int sm[256];
    int i = blockIdx.x * 256 + threadIdx.x;
    int v = (i < n) ? cnt[i] : 0;
    sm[threadIdx.x] = v;
    __syncthreads();
    for (int off = 1; off < 256; off <<= 1) {
        int t = (threadIdx.x >= off) ? sm[threadIdx.x - off] : 0;
        __syncthreads();
        sm[threadIdx.x] += t;
        __syncthreads();
    }
    if (i < n) incl[i] = sm[threadIdx.x];
    if (threadIdx.x == 255) bsums[blockIdx.x] = sm[255];
}

__global__ __launch_bounds__(512) void k_scan2(int* __restrict__ bsums, int nb) {
    __shared__ int sm[512];
    int v = (threadIdx.x < nb) ? bsums[threadIdx.x] : 0;
    sm[threadIdx.x] = v;
    __syncthreads();
    for (int off = 1; off < 512; off <<= 1) {
        int t = (threadIdx.x >= off) ? sm[threadIdx.x - off] : 0;
        __syncthreads();
        sm[threadIdx.x] += t;
        __syncthreads();
    }
    if (threadIdx.x < nb) bsums[threadIdx.x] = sm[threadIdx.x] - v;  // exclusive
}

__global__ __launch_bounds__(256) void k_scan3(const int* __restrict__ incl, const int* __restrict__ cnt,
                                               const int* __restrict__ boff, int* __restrict__ rowp,
                                               int* __restrict__ cur, int n, int Etot) {
    int i = blockIdx.x * 256 + threadIdx.x;
    if (i < n) {
        int ex = incl[i] - cnt[i] + boff[blockIdx.x];
        rowp[i] = ex;
        cur[i] = ex;
    }
    if (i == 0) rowp[n] = Etot;
}

__global__ __launch_bounds__(256) void k_scatter(const int* __restrict__ src, const int* __restrict__ dst,
                                                 const float* __restrict__ w, int* __restrict__ cur,
                                                 int* __restrict__ csrc, float* __restrict__ cw, int E) {
    int e = blockIdx.x * 256 + threadIdx.x;
    if (e < E) {
        int d = dst[e];
        int pos = atomicAdd(&cur[d], 1);
        csrc[pos] = src[e];
        if (w) cw[pos] = w[e];
    }
}

__global__ __launch_bounds__(256) void k_dinv(const float* __restrict__ deg, float* __restrict__ dinv, int N) {
    int i = blockIdx.x * 256 + threadIdx.x;
    if (i < N) dinv[i] = rsqrtf(deg[i] + 1.0f);
}

// ---------------- conversions ----------------

__global__ __launch_bounds__(256) void k_cvt_x(const float* __restrict__ in, unsigned short* __restrict__ out,
                                               int K, int Kp, long long total) {
    long long idx = (long long)blockIdx.x * 256 + threadIdx.x;
    if (idx < total) {
        int n = (int)(idx / Kp);
        int k = (int)(idx - (long long)n * Kp);
        out[idx] = (k < K) ? f2bf(in[(long long)n * K + k]) : (unsigned short)0;
    }
}

// W fp32 [K,M] -> WT bf16 [M,Kp] (rows [0,M))
__global__ __launch_bounds__(256) void k_cvt_w(const float* __restrict__ W, unsigned short* __restrict__ WT,
                                               int K, int M, int Kp) {
    int idx = blockIdx.x * 256 + threadIdx.x;
    if (idx < M * Kp) {
        int m = idx / Kp;
        int k = idx - m * Kp;
        WT[idx] = (k < K) ? f2bf(W[(long long)k * M + m]) : (unsigned short)0;
    }
}

// va rows: WT[M + t*H + h][k] = sum_c W[k][h*C+c] * a_t[h][c]   (t: 0=src, 1=dst)
// one wave per (t,h,k): coalesced read of W row segment, shuffle reduce.
__global__ __launch_bounds__(64) void k_prep_va(const float* __restrict__ W,
                                                const float* __restrict__ a_src, const float* __restrict__ a_dst,
                                                unsigned short* __restrict__ WT,
                                                int K, int M, int C, int Kp, int H) {
    int b = blockIdx.x;          // [0, 2*H*Kp)
    int k = b % Kp;
    int th = b / Kp;             // t*H + h
    int t = th / H;
    int h = th - t * H;
    size_t orow = (size_t)(M + t * H + h) * Kp;
    int lane = threadIdx.x;
    if (k >= K) {
        if (lane == 0) WT[orow + k] = 0;
        return;
    }
    const float* a = t ? a_dst : a_src;
    int hoff = h * C;
    const float* wrow = W + (size_t)k * M + hoff;
    float acc = 0.f;
    for (int c = lane; c < C; c += 64) acc += wrow[c] * a[hoff + c];
    for (int off = 32; off > 0; off >>= 1) acc += __shfl_down(acc, off);
    if (lane == 0) WT[orow + k] = f2bf(acc);
}

// ---------------- bf16 MFMA GEMM + alpha epilogue ----------------
// Cbf[N,Mp] = A[N,Kp] * BT[.,Kp]^T ; cols [0,M) -> bf16 Cbf; cols [M,M+2H) -> fp32 asb/adb

#define TBM 128
#define TBN 128
#define TBK 32
#define LDK 40

__global__ __launch_bounds__(256) void k_mfma_gemm(const unsigned short* __restrict__ A,
                                                   const unsigned short* __restrict__ BT,
                                                   unsigned short* __restrict__ Cbf,
                                                   float* __restrict__ asb, float* __restrict__ adb,
                                                   int N, int Kp, int M, int Mext, int Mp, int H) {
    __shared__ __align__(16) unsigned short As[TBM * LDK];
    __shared__ __align__(16) unsigned short Bs[TBN * LDK];
    int tid = threadIdx.x;
    int wave = tid >> 6;
    int lane = tid & 63;
    int rowBase = blockIdx.y * TBM;
    int colBase = blockIdx.x * TBN;
    int wm = (wave & 1) * 64;
    int wn = (wave >> 1) * 64;
    int l15 = lane & 15;
    int quad = lane >> 4;

    f32x4 acc[4][4];
    f32x4 z4 = {0.f, 0.f, 0.f, 0.f};
#pragma unroll
    for (int i = 0; i < 4; i++)
#pragma unroll
        for (int j = 0; j < 4; j++) acc[i][j] = z4;

    int srow = tid >> 2;
    int skg = tid & 3;
    const uint4 zero16 = {0u, 0u, 0u, 0u};

    for (int k0 = 0; k0 < Kp; k0 += TBK) {
#pragma unroll
        for (int half = 0; half < 2; half++) {
            int row = srow + half * 64;
            int gk = k0 + skg * 8;
            bool kok = (gk < Kp);
            {
                int gr = rowBase + row;
                uint4 v = zero16;
                if (kok && gr < N) v = *(const uint4*)(A + (size_t)gr * Kp + gk);
                *(uint4*)(As + row * LDK + skg * 8) = v;
            }
            {
                int gc = colBase + row;
                uint4 v = zero16;
                if (kok && gc < Mext) v = *(const uint4*)(BT + (size_t)gc * Kp + gk);
                *(uint4*)(Bs + row * LDK + skg * 8) = v;
            }
        }
        __syncthreads();

        s16x8 af[4], bfr[4];
#pragma unroll
        for (int mt = 0; mt < 4; mt++)
            af[mt] = *(const s16x8*)(As + (wm + mt * 16 + l15) * LDK + quad * 8);
#pragma unroll
        for (int nt = 0; nt < 4; nt++)
            bfr[nt] = *(const s16x8*)(Bs + (wn + nt * 16 + l15) * LDK + quad * 8);
#pragma unroll
        for (int mt = 0; mt < 4; mt++)
#pragma unroll
            for (int nt = 0; nt < 4; nt++)
                acc[mt][nt] = __builtin_amdgcn_mfma_f32_16x16x32_bf16(af[mt], bfr[nt], acc[mt][nt], 0, 0, 0);
        __syncthreads();
    }

#pragma unroll
    for (int mt = 0; mt < 4; mt++) {
#pragma unroll
        for (int r = 0; r < 4; r++) {
            int row = rowBase + wm + mt * 16 + quad * 4 + r;
            if (row < N) {
#pragma unroll
                for (int nt = 0; nt < 4; nt++) {
                    int col = colBase + wn + nt * 16 + l15;
                    float v = acc[mt][nt][r];
                    if (col < M) {
                        Cbf[(size_t)row * Mp + col] = f2bf(v);
                    } else if (asb != nullptr && col < M + 2 * H) {
                        int t = col - M;
                        if (t < H) asb[(size_t)row * H + t] = v;
                        else adb[(size_t)row * H + (t - H)] = v;
                    }
                }
            }
        }
    }
}

// ---------------- GAT aggregation: wave-parallel edge weights + shfl-broadcast gathers ----------------

__device__ __forceinline__ float lrelu02(float e) { return (e > 0.f) ? e : 0.2f * e; }

template <int CPT2, int H>
__global__ __launch_bounds__(64) void k_gat_agg(const unsigned short* __restrict__ hfeat,
                                                const float* __restrict__ as_, const float* __restrict__ ad_,
                                                const int* __restrict__ rowp, const int* __restrict__ cidx,
                                                const float* __restrict__ bias,
                                                float* __restrict__ out_f,            // final fp32 (or null)
                                                unsigned short* __restrict__ out_bf,  // next-layer bf16 (or null)
                                                int C, int ldh, int ldo, int relu) {
    int n = blockIdx.x;
    int lane = threadIdx.x;
    int HC = H * C;
    int beg = rowp[n], end = rowp[n + 1];

    int c2i[CPT2];
    bool act[CPT2];
    int hd[CPT2];
#pragma unroll
    for (int k = 0; k < CPT2; k++) {
        int c2 = 2 * (lane + k * WAVE);
        c2i[k] = c2;
        act[k] = (c2 < HC);
        hd[k] = act[k] ? (c2 / C) : 0;  // C even -> pair same head
    }

    float adn[H], msub[H], wsum[H];
#pragma unroll
    for (int h = 0; h < H; h++) {
        adn[h] = ad_[(size_t)n * H + h];
        msub[h] = lrelu02(as_[(size_t)n * H + h] + adn[h]);  // shift by self logit
        wsum[h] = 0.f;                                       // per-lane partial edge-weight sum
    }

    float accx[CPT2], accy[CPT2];
#pragma unroll
    for (int k = 0; k < CPT2; k++) {
        if (act[k]) {
            unsigned int v = *(const unsigned int*)(hfeat + (size_t)n * ldh + c2i[k]);
            accx[k] = bf2f_lo(v);  // self-loop contribution, w = exp(0) = 1
            accy[k] = bf2f_hi(v);
        } else {
            accx[k] = 0.f;
            accy[k] = 0.f;
        }
    }

    for (int base = beg; base < end; base += WAVE) {
        int cnt = end - base;
        if (cnt > WAVE) cnt = WAVE;
        // lane-parallel: edge index + weight for this chunk
        int s_l = 0;
        float w_l[H];
#pragma unroll
        for (int h = 0; h < H; h++) w_l[h] = 0.f;
        if (lane < cnt) {
            s_l = cidx[base + lane];
#pragma unroll
            for (int h = 0; h < H; h++) {
                w_l[h] = __expf(lrelu02(as_[(size_t)s_l * H + h] + adn[h]) - msub[h]);
                wsum[h] += w_l[h];
            }
        }
        // serial over chunk: broadcast s,w; gather features
        for (int j = 0; j < cnt; j++) {
            int s = __shfl(s_l, j);
            float w[H];
#pragma unroll
            for (int h = 0; h < H; h++) w[h] = __shfl(w_l[h], j);
            const unsigned short* hp = hfeat + (size_t)s * ldh;
#pragma unroll
            for (int k = 0; k < CPT2; k++) {
                if (act[k]) {
                    unsigned int v = *(const unsigned int*)(hp + c2i[k]);
                    accx[k] += w[hd[k]] * bf2f_lo(v);
                    accy[k] += w[hd[k]] * bf2f_hi(v);
                }
            }
        }
    }

    // reduce edge-weight sums across lanes (all lanes end with same value)
    float rs[H];
#pragma unroll
    for (int h = 0; h < H; h++) {
        float t = wsum[h];
        for (int off = 32; off > 0; off >>= 1) t += __shfl_xor(t, off);
        rs[h] = 1.f / (1.f + t + 1e-16f);  // +1 = self term
    }

#pragma unroll
    for (int k = 0; k < CPT2; k++) {
        int c2 = c2i[k];
        if (act[k]) {
            float o0 = accx[k] * rs[hd[k]] + bias[c2];
            float o1 = accy[k] * rs[hd[k]] + bias[c2 + 1];
            if (relu) { o0 = fmaxf(o0, 0.f); o1 = fmaxf(o1, 0.f); }
            if (out_bf) {
                unsigned int pk = (unsigned int)f2bf(o0) | ((unsigned int)f2bf(o1) << 16);
                *(unsigned int*)(out_bf + (size_t)n * ldo + c2) = pk;
            } else {
                *(float2*)(out_f + (size_t)n * HC + c2) = make_float2(o0, o1);
            }
        } else if (out_bf && c2 < ldo) {
            *(unsigned int*)(out_bf + (size_t)n * ldo + c2) = 0u;
        }
    }
}

// ---------------- GCN aggregation (bf16 in/out, pair loads) ----------------

__global__ __launch_bounds__(64) void k_gcn_agg(const unsigned short* __restrict__ hfeat, int ldh,
                                                const float* __restrict__ dinv,
                                                const int* __restrict__ rowp, const int* __restrict__ cidx,
                                                const float* __restrict__ cw, const float* __restrict__ bias,
                                                unsigned short* __restrict__ out_bf, int C, int ldo) {
    int n = blockIdx.x;
    int lane = threadIdx.x;
    float di = dinv[n];
    int beg = rowp[n], end = rowp[n + 1];
    int c2 = 2 * lane;
    bool actl = (c2 < C);

    float accx = 0.f, accy = 0.f;
    if (actl) {
        unsigned int v = *(const unsigned int*)(hfeat + (size_t)n * ldh + c2);
        accx = di * di * bf2f_lo(v);
        accy = di * di * bf2f_hi(v);
    }

    for (int base = beg; base < end; base += WAVE) {
        int cnt = end - base;
        if (cnt > WAVE) cnt = WAVE;
        int s_l = 0;
        float nm_l = 0.f;
        if (lane < cnt) {
            s_l = cidx[base + lane];
            nm_l = dinv[s_l] * cw[base + lane] * di;
        }
        for (int j = 0; j < cnt; j++) {
            int s = __shfl(s_l, j);
            float nm = __shfl(nm_l, j);
            if (actl) {
                unsigned int v = *(const unsigned int*)(hfeat + (size_t)s * ldh + c2);
                accx += nm * bf2f_lo(v);
                accy += nm * bf2f_hi(v);
            }
        }
    }

    if (c2 < ldo) {
        float o0 = 0.f, o1 = 0.f;
        if (c2 < C) o0 = fmaxf(accx + bias[c2], 0.f);
        if (c2 + 1 < C) o1 = fmaxf(accy + bias[c2 + 1], 0.f);
        unsigned int pk = (unsigned int)f2bf(o0) | ((unsigned int)f2bf(o1) << 16);
        *(unsigned int*)(out_bf + (size_t)n * ldo + c2) = pk;
    }
}

// ---------------- launch ----------------

extern "C" void kernel_launch(void* const* d_in, const int* in_sizes, int n_in,
                              void* d_out, int out_size, void* d_ws, size_t ws_size,
                              hipStream_t stream) {
    const int N_MOL = in_sizes[0] / 78;
    const int E_MOL = in_sizes[1] / 2;
    const int N_PRO = in_sizes[2] / 33;
    const int E_PRO = in_sizes[3] / 2;

    const float* mol_x = (const float*)d_in[0];
    const int* mol_ei = (const int*)d_in[1];
    const float* pro_x = (const float*)d_in[2];
    const int* pro_ei = (const int*)d_in[3];
    const float* pro_ew = (const float*)d_in[4];
    const float *W1 = (const float*)d_in[5], *as1 = (const float*)d_in[6], *ad1 = (const float*)d_in[7],
                *b1 = (const float*)d_in[8];
    const float *W2 = (const float*)d_in[9], *as2 = (const float*)d_in[10], *ad2 = (const float*)d_in[11],
                *b2 = (const float*)d_in[12];
    const float *W3 = (const float*)d_in[13], *as3 = (const float*)d_in[14], *ad3 = (const float*)d_in[15],
                *b3 = (const float*)d_in[16];
    const float *Wp1 = (const float*)d_in[17], *bp1 = (const float*)d_in[18];
    const float *Wp2 = (const float*)d_in[19], *aps2 = (const float*)d_in[20], *apd2 = (const float*)d_in[21],
                *bp2 = (const float*)d_in[22];
    const float *Wp3 = (const float*)d_in[23], *aps3 = (const float*)d_in[24], *apd3 = (const float*)d_in[25],
                *bp3 = (const float*)d_in[26];

    float* out_mol = (float*)d_out;
    float* out_pro = (float*)d_out + (size_t)N_MOL * 312;

    char* p = (char*)d_ws;
    auto alloc = [&](size_t bytes) -> void* {
        void* r = (void*)p;
        p += (bytes + 255) & ~(size_t)255;
        return r;
    };
    int* mol_rowp = (int*)alloc((size_t)(N_MOL + 1) * 4);
    int* mol_cur  = (int*)alloc((size_t)N_MOL * 4);
    int* mol_cnt  = (int*)alloc((size_t)N_MOL * 4);
    int* mol_csrc = (int*)alloc((size_t)E_MOL * 4);
    int* pro_rowp = (int*)alloc((size_t)(N_PRO + 1) * 4);
    int* pro_cur  = (int*)alloc((size_t)N_PRO * 4);
    int* pro_cnt  = (int*)alloc((size_t)N_PRO * 4);
    int* pro_csrc = (int*)alloc((size_t)E_PRO * 4);
    float* pro_csrw = (float*)alloc((size_t)E_PRO * 4);
    float* deg  = (float*)alloc((size_t)N_PRO * 4);
    float* dinv = (float*)alloc((size_t)N_PRO * 4);
    int* incl  = (int*)alloc((size_t)N_PRO * 4);
    int* bsums = (int*)alloc(512 * 4);
    float* asb = (float*)alloc((size_t)N_PRO * 2 * 4);
    float* adb = (float*)alloc((size_t)N_PRO * 2 * 4);
    unsigned short* hb = (unsigned short*)alloc((size_t)N_MOL * 320 * 2);  // GEMM out bf16
    unsigned short* xb = (unsigned short*)alloc((size_t)N_MOL * 320 * 2);  // activations bf16
    unsigned short* wt1 = (unsigned short*)alloc((size_t)160 * 80 * 2);    // 156 + 4 alpha rows
    unsigned short* wt2 = (unsigned short*)alloc((size_t)320 * 160 * 2);   // 312 + 4
    unsigned short* wt3 = (unsigned short*)alloc((size_t)320 * 320 * 2);   // 312 + 2
    unsigned short* wtp1 = (unsigned short*)alloc((size_t)40 * 40 * 2);
    unsigned short* wtp2 = (unsigned short*)alloc((size_t)136 * 40 * 2);   // 132 + 4
    unsigned short* wtp3 = (unsigned short*)alloc((size_t)136 * 136 * 2);  // 132 + 2
    (void)ws_size;

    const int* mol_src = mol_ei;
    const int* mol_dst = mol_ei + E_MOL;
    const int* pro_src = pro_ei;
    const int* pro_dst = pro_ei + E_PRO;

    // ---- build CSR (by dst) ----
    hipMemsetAsync(mol_cnt, 0, (size_t)N_MOL * 4, stream);
    hipMemsetAsync(pro_cnt, 0, (size_t)N_PRO * 4, stream);
    hipMemsetAsync(deg, 0, (size_t)N_PRO * 4, stream);

    k_count<<<(E_MOL + 255) / 256, 256, 0, stream>>>(mol_dst, mol_cnt, nullptr, nullptr, E_MOL);
    k_count<<<(E_PRO + 255) / 256, 256, 0, stream>>>(pro_dst, pro_cnt, pro_ew, deg, E_PRO);

    int nbM = (N_MOL + 255) / 256;
    k_scan1<<<nbM, 256, 0, stream>>>(mol_cnt, incl, bsums, N_MOL);
    k_scan2<<<1, 512, 0, stream>>>(bsums, nbM);
    k_scan3<<<nbM, 256, 0, stream>>>(incl, mol_cnt, bsums, mol_rowp, mol_cur, N_MOL, E_MOL);
    k_scatter<<<(E_MOL + 255) / 256, 256, 0, stream>>>(mol_src, mol_dst, nullptr, mol_cur, mol_csrc, nullptr, E_MOL);

    int nbP = (N_PRO + 255) / 256;
    k_scan1<<<nbP, 256, 0, stream>>>(pro_cnt, incl, bsums, N_PRO);
    k_scan2<<<1, 512, 0, stream>>>(bsums, nbP);
    k_scan3<<<nbP, 256, 0, stream>>>(incl, pro_cnt, bsums, pro_rowp, pro_cur, N_PRO, E_PRO);
    k_scatter<<<(E_PRO + 255) / 256, 256, 0, stream>>>(pro_src, pro_dst, pro_ew, pro_cur, pro_csrc, pro_csrw, E_PRO);

    k_dinv<<<(N_PRO + 255) / 256, 256, 0, stream>>>(deg, dinv, N_PRO);

    // ---- weight converts + fused alpha-vector rows ----
    auto cvtw = [&](const float* W, unsigned short* WT, int K, int M, int Kp) {
        k_cvt_w<<<(M * Kp + 255) / 256, 256, 0, stream>>>(W, WT, K, M, Kp);
    };
    cvtw(W1, wt1, 78, 156, 80);
    cvtw(W2, wt2, 156, 312, 160);
    cvtw(W3, wt3, 312, 312, 320);
    cvtw(Wp1, wtp1, 33, 33, 40);
    cvtw(Wp2, wtp2, 33, 132, 40);
    cvtw(Wp3, wtp3, 132, 132, 136);
    // one wave per (t,h,k): grid = 2*H*Kp
    k_prep_va<<<2 * 2 * 80, 64, 0, stream>>>(W1, as1, ad1, wt1, 78, 156, 78, 80, 2);
    k_prep_va<<<2 * 2 * 160, 64, 0, stream>>>(W2, as2, ad2, wt2, 156, 312, 156, 160, 2);
    k_prep_va<<<2 * 1 * 320, 64, 0, stream>>>(W3, as3, ad3, wt3, 312, 312, 312, 320, 1);
    k_prep_va<<<2 * 2 * 40, 64, 0, stream>>>(Wp2, aps2, apd2, wtp2, 33, 132, 66, 40, 2);
    k_prep_va<<<2 * 1 * 136, 64, 0, stream>>>(Wp3, aps3, apd3, wtp3, 132, 132, 132, 136, 1);

    auto gemm = [&](const unsigned short* A, const unsigned short* BT, unsigned short* C,
                    float* as_o, float* ad_o, int N, int Kp, int M, int Mp, int H) {
        int Mext = (as_o != nullptr) ? (M + 2 * H) : M;
        dim3 grid((Mext + TBN - 1) / TBN, (N + TBM - 1) / TBM);
        k_mfma_gemm<<<grid, 256, 0, stream>>>(A, BT, C, as_o, ad_o, N, Kp, M, Mext, Mp, H);
    };

    // ---- mol branch ----
    {
        long long tot = (long long)N_MOL * 80;
        k_cvt_x<<<(int)((tot + 255) / 256), 256, 0, stream>>>(mol_x, xb, 78, 80, tot);
    }
    // conv1: GAT 78 -> 78, H=2 (HC=156), relu
    gemm(xb, wt1, hb, asb, adb, N_MOL, 80, 156, 160, 2);
    k_gat_agg<2, 2><<<N_MOL, 64, 0, stream>>>(hb, asb, adb, mol_rowp, mol_csrc, b1, nullptr, xb, 78, 160, 160, 1);
    // conv2: GAT 156 -> 156, H=2 (HC=312), relu
    gemm(xb, wt2, hb, asb, adb, N_MOL, 160, 312, 320, 2);
    k_gat_agg<3, 2><<<N_MOL, 64, 0, stream>>>(hb, asb, adb, mol_rowp, mol_csrc, b2, nullptr, xb, 156, 320, 320, 1);
    // conv3: GAT 312 -> 312, H=1, no relu -> fp32 out
    gemm(xb, wt3, hb, asb, adb, N_MOL, 320, 312, 320, 1);
    k_gat_agg<3, 1><<<N_MOL, 64, 0, stream>>>(hb, asb, adb, mol_rowp, mol_csrc, b3, out_mol, nullptr, 312, 320, 0, 0);

    // ---- pro branch ----
    {
        long long tot = (long long)N_PRO * 40;
        k_cvt_x<<<(int)((tot + 255) / 256), 256, 0, stream>>>(pro_x, xb, 33, 40, tot);
    }
    // gcn: 33 -> 33, relu
    gemm(xb, wtp1, hb, nullptr, nullptr, N_PRO, 40, 33, 40, 0);
    k_gcn_agg<<<N_PRO, 64, 0, stream>>>(hb, 40, dinv, pro_rowp, pro_csrc, pro_csrw, bp1, xb, 33, 40);
    // conv2: GAT 33 -> 66, H=2 (HC=132), relu
    gemm(xb, wtp2, hb, asb, adb, N_PRO, 40, 132, 136, 2);
    k_gat_agg<2, 2><<<N_PRO, 64, 0, stream>>>(hb, asb, adb, pro_rowp, pro_csrc, bp2, nullptr, xb, 66, 136, 136, 1);
    // conv3: GAT 132 -> 132, H=1, relu -> fp32 out
    gemm(xb, wtp3, hb, asb, adb, N_PRO, 136, 132, 136, 1);
    k_gat_agg<2, 1><<<N_PRO, 64, 0, stream>>>(hb, asb, adb, pro_rowp, pro_csrc, bp3, out_pro, nullptr, 132, 136, 0, 1);
}